// Round 5
// baseline (206.266 us; speedup 1.0000x reference)
//
#include <hip/hip_runtime.h>

// ---- types ----
typedef __attribute__((ext_vector_type(8))) short  bf16x8;  // 8 bf16 = 4 VGPR
typedef __attribute__((ext_vector_type(4))) float  f32x4;

static __device__ __forceinline__ unsigned short f2bf(float f) {
    unsigned u = __float_as_uint(f);
    u += 0x7fffu + ((u >> 16) & 1u);      // RNE (inputs are finite)
    return (unsigned short)(u >> 16);
}

// ---------------------------------------------------------------------------
// Prep: At[bn][n][k] = bf16(A[bn][k][n]); 32*128*128 bf16 = 1 MB into d_ws.
// ---------------------------------------------------------------------------
__global__ __launch_bounds__(256) void prep_at_kernel(
        const float* __restrict__ A, unsigned short* __restrict__ At)
{
    int g   = blockIdx.x * 256 + threadIdx.x;   // 65536 total
    int bn  = g >> 11;
    int rem = g & 2047;
    int kc  = rem >> 7;                         // k octet
    int n   = rem & 127;

    const float* src = A + bn * 16384 + kc * 8 * 128 + n;
    unsigned h[4];
    #pragma unroll
    for (int j = 0; j < 4; ++j) {
        unsigned short lo = f2bf(src[(2 * j    ) * 128]);
        unsigned short hi = f2bf(src[(2 * j + 1) * 128]);
        h[j] = (unsigned)lo | ((unsigned)hi << 16);
    }
    uint4 pk = make_uint4(h[0], h[1], h[2], h[3]);
    *(uint4*)(At + bn * 16384 + n * 128 + kc * 8) = pk;
}

// ---------------------------------------------------------------------------
// Main: wave-independent streaming, ZERO in-loop barriers.
// Grid 768 = 32 bn x 24 persistent blocks; block = 256 thr = 4 waves.
// Prologue: At block (32 KB bf16, [n][k]) -> LDS via global_load_lds with
// XOR-swizzle (slot ^= n&7 within each 256B row; involution applied to the
// SOURCE address, LDS dest linear; frag reads apply the same XOR -> bank-even
// 8 accesses/bank for b128, i.e. conflict-free baseline). One __syncthreads.
// Main loop: each wave owns rows [job*64 + wid*16, +16) x all 128 cols.
// v streamed global->reg (8 float4/lane) with named double buffers stA/stB,
// 2-unrolled loop: compute(stA) runs while stB's loads are in flight; the
// compiler's per-value waitcnt gives counted (non-zero) vmcnt -> waves
// self-stagger and HBM issue is continuous. cvt f32->bf16 once per element.
// acc[8] f32x4 covers 16 rows x 128 cols; fused dx@B^T + bias + ReLU store.
// launch_bounds(256,3): VGPR cap 170 (natural ~150), 12 waves/CU = 3 blocks,
// LDS 3x32 KB = 96 KB -> in-flight ~12x8 KB = 96 KB/CU.
// ---------------------------------------------------------------------------
__global__ __launch_bounds__(256, 3) void trans_main_kernel(
        const float* __restrict__ v,  const float* __restrict__ dx,
        const unsigned short* __restrict__ At, const float* __restrict__ Bm,
        const float* __restrict__ bsc, float* __restrict__ out)
{
    __shared__ unsigned short AtL[128 * 128];   // 32 KB, [n][k] bf16, swizzled

    const int tid = threadIdx.x;
    const int wid = tid >> 6;
    const int l   = tid & 63;
    const int lr  = l & 15;
    const int lq  = l >> 4;
    const int bn   = blockIdx.x / 24;           // 0..31
    const int bidx = blockIdx.x - bn * 24;      // 0..23

    // ---- stage At -> LDS (linear dest, inverse-swizzled source) ----
    {
        const unsigned short* src = At + bn * 16384;
        #pragma unroll
        for (int it = 0; it < 8; ++it) {
            int c16 = it * 256 + tid;           // 16B-chunk index (0..2047)
            int n   = c16 >> 4;                 // row (col index of block)
            int c   = c16 & 15;                 // 16B slot within 256B row
            int sc  = c ^ (n & 7);              // involution
            __builtin_amdgcn_global_load_lds(
                (const __attribute__((address_space(1))) unsigned int*)
                    (src + n * 128 + sc * 8),
                (__attribute__((address_space(3))) unsigned int*)
                    ((char*)AtL + c16 * 16),
                16, 0, 0);
        }
    }

    const float bias = *bsc;
    const int col0 = bn * 128;
    float2 bc[8];
    #pragma unroll
    for (int ni = 0; ni < 8; ++ni)
        bc[ni] = *(const float2*)(Bm + 2 * (col0 + ni * 16 + lr));

    __syncthreads();                            // AtL ready; read-only after

    // ---- LDS frag addressing: addr = nb[ni] + xr[kq] ----
    const char* AtB = (const char*)AtL;
    int nb[8], xr[4];
    #pragma unroll
    for (int ni = 0; ni < 8; ++ni) nb[ni] = (ni * 16 + lr) * 256;
    #pragma unroll
    for (int kq = 0; kq < 4; ++kq) xr[kq] = (((kq * 4 + lq) ^ (lr & 7)) << 4);

    const int njobs = (256 - bidx + 23) / 24;   // 10 or 11 (64-row jobs)

    auto vload = [&](float4 (&st)[8], int job) {
        const float* p = v + (size_t)(job * 64 + wid * 16 + lr) * 4096
                           + col0 + lq * 8;
        #pragma unroll
        for (int kq = 0; kq < 4; ++kq) {
            st[kq * 2    ] = *(const float4*)(p + kq * 32);
            st[kq * 2 + 1] = *(const float4*)(p + kq * 32 + 4);
        }
    };

    auto compute = [&](const float4 (&st)[8], int job) {
        f32x4 acc[8];
        #pragma unroll
        for (int ni = 0; ni < 8; ++ni) acc[ni] = (f32x4){0.f, 0.f, 0.f, 0.f};
        #pragma unroll
        for (int kq = 0; kq < 4; ++kq) {
            const float4 f0 = st[kq * 2], f1 = st[kq * 2 + 1];
            union { bf16x8 vv; unsigned short s[8]; } u;
            u.s[0] = f2bf(f0.x); u.s[1] = f2bf(f0.y);
            u.s[2] = f2bf(f0.z); u.s[3] = f2bf(f0.w);
            u.s[4] = f2bf(f1.x); u.s[5] = f2bf(f1.y);
            u.s[6] = f2bf(f1.z); u.s[7] = f2bf(f1.w);
            #pragma unroll
            for (int ni = 0; ni < 8; ++ni) {
                bf16x8 bq = *(const bf16x8*)(AtB + nb[ni] + xr[kq]);
                acc[ni] = __builtin_amdgcn_mfma_f32_16x16x32_bf16(
                              u.vv, bq, acc[ni], 0, 0, 0);
            }
        }
        // ---- fused epilogue: + dx @ B^T + b, ReLU, store ----
        #pragma unroll
        for (int jj = 0; jj < 4; ++jj) {
            const int rowg = job * 64 + wid * 16 + lq * 4 + jj;
            const float2 d = *(const float2*)(dx + 2 * rowg);
            float* orow = out + (size_t)rowg * 4096 + col0 + lr;
            #pragma unroll
            for (int ni = 0; ni < 8; ++ni) {
                float val = acc[ni][jj] + d.x * bc[ni].x + d.y * bc[ni].y + bias;
                orow[ni * 16] = fmaxf(val, 0.0f);
            }
        }
    };

    // ---- 2-unrolled software pipeline, named reg double buffers ----
    float4 stA[8], stB[8];
    int i = 0;
    vload(stA, bidx);
    while (i + 2 <= njobs) {
        vload(stB, bidx + (i + 1) * 24);
        compute(stA, bidx + i * 24);
        if (i + 2 < njobs) vload(stA, bidx + (i + 2) * 24);
        compute(stB, bidx + (i + 1) * 24);
        i += 2;
    }
    if (i < njobs) compute(stA, bidx + i * 24);   // odd tail (stA loaded)
}

// ---------------------------------------------------------------------------
extern "C" void kernel_launch(void* const* d_in, const int* in_sizes, int n_in,
                              void* d_out, int out_size, void* d_ws, size_t ws_size,
                              hipStream_t stream)
{
    const float* v  = (const float*)d_in[0];   // [16384, 4096]
    const float* dx = (const float*)d_in[1];   // [16384, 2]
    const float* A  = (const float*)d_in[2];   // [32, 128, 128]
    const float* Bm = (const float*)d_in[3];   // [4096, 2]
    const float* b  = (const float*)d_in[4];   // scalar

    unsigned short* At = (unsigned short*)d_ws; // 1 MB: [32][128 n][128 k] bf16

    prep_at_kernel<<<dim3(256), dim3(256), 0, stream>>>(A, At);
    trans_main_kernel<<<dim3(768), dim3(256), 0, stream>>>(v, dx, At, Bm, b,
                                                           (float*)d_out);
}

// Round 6
// 104.768 us; speedup vs baseline: 1.9688x; 1.9688x over previous
//
#include <hip/hip_runtime.h>

// ---- types ----
typedef __attribute__((ext_vector_type(8))) short  bf16x8;  // 8 bf16 = 4 VGPR
typedef __attribute__((ext_vector_type(4))) float  f32x4;

static __device__ __forceinline__ unsigned short f2bf(float f) {
    unsigned u = __float_as_uint(f);
    u += 0x7fffu + ((u >> 16) & 1u);      // RNE (inputs are finite)
    return (unsigned short)(u >> 16);
}

// ---------------------------------------------------------------------------
// Prep: At[bn][n][k] = bf16(A[bn][k][n]); 32*128*128 bf16 = 1 MB into d_ws.
// ---------------------------------------------------------------------------
__global__ __launch_bounds__(256) void prep_at_kernel(
        const float* __restrict__ A, unsigned short* __restrict__ At)
{
    int g   = blockIdx.x * 256 + threadIdx.x;   // 65536 total
    int bn  = g >> 11;
    int rem = g & 2047;
    int kc  = rem >> 7;                         // k octet
    int n   = rem & 127;

    const float* src = A + bn * 16384 + kc * 8 * 128 + n;
    unsigned h[4];
    #pragma unroll
    for (int j = 0; j < 4; ++j) {
        unsigned short lo = f2bf(src[(2 * j    ) * 128]);
        unsigned short hi = f2bf(src[(2 * j + 1) * 128]);
        h[j] = (unsigned)lo | ((unsigned)hi << 16);
    }
    uint4 pk = make_uint4(h[0], h[1], h[2], h[3]);
    *(uint4*)(At + bn * 16384 + n * 128 + kc * 8) = pk;
}

// ---------------------------------------------------------------------------
// Main (R2 skeleton + T3/T4 counted-vmcnt pipeline):
// Grid 512 = 32 bn x 16; 512 threads = 8 waves (wm=wid>>2, wn=wid&3), wave
// owns 16 rows x 32 cols per tile. At block -> registers once (bq[4][2]).
// v tile 32x128 f32 in LDS, THREE buffers (48 KB), depth-2 prefetch via
// global_load_lds (XOR-swizzle (row&7)<<4 applied to pre-swizzled global
// source + swizzled LDS read; dest linear). Per tile:
//   s_waitcnt vmcnt(12)  -- own S(k) landed; 12 <= min ops issued after S(k)
//                           (stage 2 + dx 4 + stores 8 of later iters),
//                           valid for all k>=1 incl. tails (in-order retire)
//   s_barrier            -- everyone's S(k) landed; buf (k+2)%3 free
//   sched_barrier(0)     -- rule #18 fence
//   issue S(k+2); compute(k); fused epilogue stores(k)
// Loads never drain to 0 -> continuous HBM issue across barriers.
// ---------------------------------------------------------------------------
__global__ __launch_bounds__(512, 4) void trans_main_kernel(
        const float* __restrict__ v,  const float* __restrict__ dx,
        const unsigned short* __restrict__ At, const float* __restrict__ Bm,
        const float* __restrict__ bsc, float* __restrict__ out)
{
    __shared__ float lds[3][32 * 128];          // 48 KB

    const int tid = threadIdx.x;
    const int wid = tid >> 6;
    const int l   = tid & 63;
    const int lr  = l & 15;
    const int lq  = l >> 4;
    const int wm  = wid >> 2;                   // 0..1 (16-row half)
    const int wn  = wid & 3;                    // 0..3 (32-col quarter)
    const int bn     = blockIdx.x >> 4;         // 0..31
    const int mtbase = blockIdx.x & 15;         // 0..15

    // ---- At block -> registers, once. b-frag: B[k=lq*8+j][n=col] ----
    bf16x8 bq[4][2];
    const unsigned short* atb = At + bn * 16384 + (wn * 32 + lr) * 128 + lq * 8;
    #pragma unroll
    for (int kq = 0; kq < 4; ++kq)
        #pragma unroll
        for (int ni = 0; ni < 2; ++ni)
            bq[kq][ni] = *(const bf16x8*)(atb + ni * 16 * 128 + kq * 32);

    // ---- epilogue constants ----
    const float bias = *bsc;
    const int col0 = bn * 128 + wn * 32;
    float2 bc[2];
    #pragma unroll
    for (int ni = 0; ni < 2; ++ni)
        bc[ni] = *(const float2*)(Bm + 2 * (col0 + ni * 16 + lr));

    // ---- async stage of one 32x128 tile (pre-swizzled source) ----
    auto stage = [&](int buf, int k) {
        const float* src = v + (size_t)(k * 16 + mtbase) * 32 * 4096 + bn * 128;
        #pragma unroll
        for (int it = 0; it < 2; ++it) {
            int c16  = it * 512 + tid;          // 16B-chunk index (0..1023)
            int row  = c16 >> 5;                // 32 chunks per 512B row
            int off  = (c16 & 31) << 4;
            int soff = off ^ ((row & 7) << 4);  // inverse-swizzled source
            const float* g = src + (size_t)row * 4096 + (soff >> 2);
            __builtin_amdgcn_global_load_lds(
                (const __attribute__((address_space(1))) unsigned int*)g,
                (__attribute__((address_space(3))) unsigned int*)
                    &lds[buf][c16 * 4],
                16, 0, 0);
        }
    };

    // ---- compute + fused epilogue for tile k from buffer buf ----
    auto body = [&](int buf, int k) {
        const int mt = k * 16 + mtbase;
        f32x4 acc[2];
        acc[0] = (f32x4){0.f, 0.f, 0.f, 0.f};
        acc[1] = (f32x4){0.f, 0.f, 0.f, 0.f};

        const char* Lb = (const char*)&lds[buf][0];
        const int row = wm * 16 + lr;
        const int rb  = row * 512;
        const int m   = (row & 7) << 4;
        #pragma unroll
        for (int kq = 0; kq < 4; ++kq) {
            const int base = kq * 128 + lq * 32;
            float4 f0 = *(const float4*)(Lb + rb + ((base     ) ^ m));
            float4 f1 = *(const float4*)(Lb + rb + ((base + 16) ^ m));
            union { bf16x8 vv; unsigned short s[8]; } u;
            u.s[0] = f2bf(f0.x); u.s[1] = f2bf(f0.y);
            u.s[2] = f2bf(f0.z); u.s[3] = f2bf(f0.w);
            u.s[4] = f2bf(f1.x); u.s[5] = f2bf(f1.y);
            u.s[6] = f2bf(f1.z); u.s[7] = f2bf(f1.w);
            acc[0] = __builtin_amdgcn_mfma_f32_16x16x32_bf16(
                         u.vv, bq[kq][0], acc[0], 0, 0, 0);
            acc[1] = __builtin_amdgcn_mfma_f32_16x16x32_bf16(
                         u.vv, bq[kq][1], acc[1], 0, 0, 0);
        }

        #pragma unroll
        for (int jj = 0; jj < 4; ++jj) {
            const int rowg = mt * 32 + wm * 16 + lq * 4 + jj;
            const float2 d = *(const float2*)(dx + 2 * rowg);
            float* orow = out + (size_t)rowg * 4096 + col0 + lr;
            float v0 = acc[0][jj] + d.x * bc[0].x + d.y * bc[0].y + bias;
            float v1 = acc[1][jj] + d.x * bc[1].x + d.y * bc[1].y + bias;
            orow[0]  = fmaxf(v0, 0.0f);
            orow[16] = fmaxf(v1, 0.0f);
        }
    };

    // ---- pipeline: depth-2 prefetch, counted vmcnt, raw barriers ----
    stage(0, 0);                                // S(0)
    stage(1, 1);                                // S(1)

    // iter 0 (peeled: only S(1)'s 2 loads may stay outstanding)
    asm volatile("s_waitcnt vmcnt(2) lgkmcnt(0)" ::: "memory");
    __builtin_amdgcn_s_barrier();
    __builtin_amdgcn_sched_barrier(0);
    stage(2, 2);                                // S(2)
    body(0, 0);

    for (int k = 1; k < 32; ++k) {
        asm volatile("s_waitcnt vmcnt(12) lgkmcnt(0)" ::: "memory");
        __builtin_amdgcn_s_barrier();
        __builtin_amdgcn_sched_barrier(0);
        if (k + 2 < 32) stage((k + 2) % 3, k + 2);
        body(k % 3, k);
    }
}

// ---------------------------------------------------------------------------
extern "C" void kernel_launch(void* const* d_in, const int* in_sizes, int n_in,
                              void* d_out, int out_size, void* d_ws, size_t ws_size,
                              hipStream_t stream)
{
    const float* v  = (const float*)d_in[0];   // [16384, 4096]
    const float* dx = (const float*)d_in[1];   // [16384, 2]
    const float* A  = (const float*)d_in[2];   // [32, 128, 128]
    const float* Bm = (const float*)d_in[3];   // [4096, 2]
    const float* b  = (const float*)d_in[4];   // scalar

    unsigned short* At = (unsigned short*)d_ws; // 1 MB: [32][128 n][128 k] bf16

    prep_at_kernel<<<dim3(256), dim3(256), 0, stream>>>(A, At);
    trans_main_kernel<<<dim3(512), dim3(512), 0, stream>>>(v, dx, At, Bm, b,
                                                           (float*)d_out);
}